// Round 12
// baseline (154.282 us; speedup 1.0000x reference)
//
#include <hip/hip_runtime.h>
#include <hip/hip_bf16.h>

// x [B=4][C=256][N=4096] fp32 -> attention [B][N][N] fp32 (row softmax of cosine sim)
#define BATCH 4
#define CDIM  256
#define NTOK  4096

#define BM 64      // rows per block (all waves cover all 64 rows)
#define BN 256     // tokens per ct tile; ring slot = 256 tok x 64 k = 32 KB

typedef short bf16x8 __attribute__((ext_vector_type(8)));
typedef float floatx4 __attribute__((ext_vector_type(4)));
typedef unsigned int uintx4 __attribute__((ext_vector_type(4)));
typedef unsigned int u32;

#define PIN(v) asm volatile("" : "+v"(v))
#define WAIT(n) asm volatile("s_waitcnt vmcnt(" #n ")" ::: "memory")
#define BAR() do { __builtin_amdgcn_s_barrier(); asm volatile("" ::: "memory"); } while (0)

__device__ inline u32 f2bf1(float f) {
    u32 u = __float_as_uint(f);
    u += 0x7fffu + ((u >> 16) & 1u);   // RTNE
    return u >> 16;
}
__device__ inline u32 f2bf2(float lo, float hi) { return f2bf1(lo) | (f2bf1(hi) << 16); }

__device__ inline void gload_lds16(const short* g, short* l) {
    __builtin_amdgcn_global_load_lds(
        (const __attribute__((address_space(1))) u32*)g,
        (__attribute__((address_space(3))) u32*)l, 16, 0, 0);
}

// ---------- prep: x [B][C][N] f32 -> xn [B][N][C] bf16, rows normalized to unit L2 ----------
#define TT 32
__global__ __launch_bounds__(256) void prep_kernel(const float* __restrict__ x,
                                                   short* __restrict__ xn) {
    __shared__ float tile[TT][CDIM + 2];
    __shared__ float part[8][TT];
    __shared__ float rinv_s[TT];
    const int tid = threadIdx.x;
    const int blk = blockIdx.x;            // 0..511
    const int b = blk >> 7;
    const int t0 = (blk & 127) * TT;
    const float* xb = x + (size_t)b * CDIM * NTOK;
    const int ti = tid & 31, cq = tid >> 5;
    float ss = 0.f;
    for (int c = cq; c < CDIM; c += 8) {
        float v = xb[(size_t)c * NTOK + t0 + ti];
        tile[ti][c] = v;
        ss += v * v;
    }
    part[cq][ti] = ss;
    __syncthreads();
    if (tid < TT) {
        float s = 0.f;
#pragma unroll
        for (int q = 0; q < 8; ++q) s += part[q][tid];
        rinv_s[tid] = 1.0f / sqrtf(s);
    }
    __syncthreads();
    const int tok = tid >> 3, seg = tid & 7;
    const float ri = rinv_s[tok];
    size_t obase = ((size_t)(b * NTOK + t0 + tok)) * CDIM + seg * 32;
#pragma unroll
    for (int j = 0; j < 4; ++j) {
        u32 w[4];
#pragma unroll
        for (int u = 0; u < 4; ++u) {
            float f0 = tile[tok][seg * 32 + j * 8 + 2 * u] * ri;
            float f1 = tile[tok][seg * 32 + j * 8 + 2 * u + 1] * ri;
            w[u] = f2bf2(f0, f1);
        }
        *(uintx4*)&xn[obase + j * 8] = (uintx4){w[0], w[1], w[2], w[3]};
    }
}

// ---------- fused two-sweep GEMM + softmax, fat phases ----------
// 8 waves, each owns ALL 64 rows x 32 cols (1x8 split): A = 64 rows x K=256 in
// 128 pinned VGPRs per wave (duplicated across waves — registers are free),
// so LDS B-read volume = 1.0x staged bytes. Ring slot = [256 tok][64 k] = 32 KB,
// 4 slots; 16 MFMA + 4 ds_read_b128 per wave per phase; counted vmcnt.
// XOR swizzle: 16B-pos p of row tr holds logical chunk p ^ (tr&7).
__global__ __launch_bounds__(512, 2) void attn_kernel(const short* __restrict__ xn,
                                                      float* __restrict__ out) {
    __shared__ short Bs[4][256][64];      // 4 x 32 KB ring
    __shared__ float rowsumLds[BM][8];
    const int tid = threadIdx.x;
    const int D = blockIdx.x;
    const int b = D >> 6;
    const int rb = (D & 63) * BM;
    const short* xnb = xn + (size_t)b * NTOK * CDIM;
    float* outb = out + ((size_t)b << 24);
    const int lane = tid & 63, wid = tid >> 6;     // 8 waves: 1 row-group x 8 col-groups
    const int wcol = wid << 5;                     // 0,32,...,224
    const int r0 = lane & 15, kq = lane >> 4;
    const int sx = r0 & 7;
    const int tr0 = wcol + r0, tr1 = wcol + 16 + r0;

    // staging roles: thread -> token trl (+64*rr), 16B-pos lane&7, inverse swizzle
    const int trl = (wid << 3) + (lane >> 3);      // 0..63
    const int c8 = (lane & 7) ^ (lane >> 3);

    // A fragments: ALL 64 rows (rb + m*16 + r0), full K=256, PINNED (128 VGPR)
    bf16x8 afr[4][8];
#pragma unroll
    for (int m = 0; m < 4; ++m) {
        const short* arow = xnb + (size_t)(rb + m * 16 + r0) * CDIM;
#pragma unroll
        for (int j = 0; j < 8; ++j) {
            afr[m][j] = *(const bf16x8*)(arow + j * 32 + kq * 8);
            PIN(afr[m][j]);
        }
    }

    // psum holds rowsums during sweep 0, then becomes rinv in-place. [m*4+r]
    float psum[16];
#pragma unroll
    for (int i = 0; i < 16; ++i) psum[i] = 0.f;
    floatx4 acc[4][2];

    // stage slot kc of ct-tile: 4 gloads per thread (rr = 0..3)
    auto stage = [&](int ct, int kc) {
        const short* s0 = xnb + (size_t)(ct * BN + trl) * CDIM + kc * 64 + c8 * 8;
        short* d = &Bs[kc][wid << 3][0];
#pragma unroll
        for (int rr = 0; rr < 4; ++rr)
            gload_lds16(s0 + (size_t)(rr * 64) * CDIM, d + rr * 64 * 64);
    };

#define ACCZERO() do { _Pragma("unroll") for (int m = 0; m < 4; ++m) { \
        acc[m][0] = (floatx4){0,0,0,0}; acc[m][1] = (floatx4){0,0,0,0}; } } while (0)

#define COMPUTE(KC) do { \
    __builtin_amdgcn_s_setprio(1); \
    const int p0 = kq ^ sx, p1 = (4 | kq) ^ sx; \
    bf16x8 b00 = *(const bf16x8*)&Bs[KC][tr0][p0 * 8]; \
    bf16x8 b10 = *(const bf16x8*)&Bs[KC][tr1][p0 * 8]; \
    bf16x8 b01 = *(const bf16x8*)&Bs[KC][tr0][p1 * 8]; \
    bf16x8 b11 = *(const bf16x8*)&Bs[KC][tr1][p1 * 8]; \
    _Pragma("unroll") for (int m = 0; m < 4; ++m) \
        acc[m][0] = __builtin_amdgcn_mfma_f32_16x16x32_bf16(afr[m][(KC)*2], b00, acc[m][0], 0,0,0); \
    _Pragma("unroll") for (int m = 0; m < 4; ++m) \
        acc[m][1] = __builtin_amdgcn_mfma_f32_16x16x32_bf16(afr[m][(KC)*2], b10, acc[m][1], 0,0,0); \
    _Pragma("unroll") for (int m = 0; m < 4; ++m) \
        acc[m][0] = __builtin_amdgcn_mfma_f32_16x16x32_bf16(afr[m][(KC)*2+1], b01, acc[m][0], 0,0,0); \
    _Pragma("unroll") for (int m = 0; m < 4; ++m) \
        acc[m][1] = __builtin_amdgcn_mfma_f32_16x16x32_bf16(afr[m][(KC)*2+1], b11, acc[m][1], 0,0,0); \
    __builtin_amdgcn_s_setprio(0); \
} while (0)

#define STEP(KC, SCT, SKC, WN) do { stage((SCT), (SKC)); WAIT(WN); BAR(); COMPUTE(KC); } while (0)
#define STEPNS(KC, WN)        do { WAIT(WN); BAR(); COMPUTE(KC); } while (0)

#define EPI0() do { \
    _Pragma("unroll") for (int m = 0; m < 4; ++m) \
    _Pragma("unroll") for (int r = 0; r < 4; ++r) \
        psum[m * 4 + r] += __expf(acc[m][0][r] - 1.f) + __expf(acc[m][1][r] - 1.f); \
} while (0)

#define EPI1(CT) do { \
    _Pragma("unroll") for (int m = 0; m < 4; ++m) \
    _Pragma("unroll") for (int r = 0; r < 4; ++r) { \
        const int row = rb + m * 16 + kq * 4 + r; \
        float* p = outb + ((size_t)row << 12) + ((CT) << 8) + wcol + r0; \
        const float ri = psum[m * 4 + r]; \
        __builtin_nontemporal_store(__expf(acc[m][0][r] - 1.f) * ri, p); \
        __builtin_nontemporal_store(__expf(acc[m][1][r] - 1.f) * ri, p + 16); } \
} while (0)

    // ================= sweep 0: rowsums =================
    stage(0, 0); stage(0, 1);
    for (int ct = 0; ct < 15; ++ct) {
        ACCZERO();
        STEP(0, ct, 2, 8);
        STEP(1, ct, 3, 8);
        STEP(2, ct + 1, 0, 8);
        STEP(3, ct + 1, 1, 8);
        EPI0();
    }
    ACCZERO();
    STEP(0, 15, 2, 8);
    STEP(1, 15, 3, 8);
    STEPNS(2, 4);
    STEPNS(3, 0);
    EPI0();

    // rowsum reduce across 16 r0-lanes, then across 8 col-waves -> rinv (into psum)
#pragma unroll
    for (int m = 0; m < 4; ++m)
#pragma unroll
        for (int r = 0; r < 4; ++r) {
            float v = psum[m * 4 + r];
            v += __shfl_xor(v, 1); v += __shfl_xor(v, 2);
            v += __shfl_xor(v, 4); v += __shfl_xor(v, 8);
            if (r0 == 0) rowsumLds[m * 16 + kq * 4 + r][wid] = v;
        }
    __syncthreads();
#pragma unroll
    for (int m = 0; m < 4; ++m)
#pragma unroll
        for (int r = 0; r < 4; ++r) {
            const int row = m * 16 + kq * 4 + r;
            float s = 0.f;
#pragma unroll
            for (int w = 0; w < 8; ++w) s += rowsumLds[row][w];
            psum[m * 4 + r] = 1.0f / s;
        }
    __syncthreads();   // also guards ring reuse below

    // ================= sweep 1: normalized stores =================
    stage(0, 0); stage(0, 1);
    {   // ct = 0 peeled (no stores outstanding yet)
        ACCZERO();
        STEP(0, 0, 2, 8);
        STEP(1, 0, 3, 8);
        STEP(2, 1, 0, 8);
        STEP(3, 1, 1, 8);
        EPI1(0);           // 32 stores enter the vmcnt queue
    }
    for (int ct = 1; ct < 15; ++ct) {
        ACCZERO();
        STEP(0, ct, 2, 40);      // queue: [G,G,S(32),Gnew] -> need oldest G
        STEP(1, ct, 3, 40);
        STEP(2, ct + 1, 0, 8);   // forces prev-ct stores drained (2 steps old)
        STEP(3, ct + 1, 1, 8);
        EPI1(ct);
    }
    ACCZERO();
    STEP(0, 15, 2, 40);
    STEP(1, 15, 3, 40);
    STEPNS(2, 4);
    STEPNS(3, 0);
    EPI1(15);

#undef ACCZERO
#undef COMPUTE
#undef STEP
#undef STEPNS
#undef EPI0
#undef EPI1
}

extern "C" void kernel_launch(void* const* d_in, const int* in_sizes, int n_in,
                              void* d_out, int out_size, void* d_ws, size_t ws_size,
                              hipStream_t stream) {
    const float* x = (const float*)d_in[0];
    float* out = (float*)d_out;
    short* xn = (short*)d_ws;    // [B][N][C] bf16 = 8 MB

    prep_kernel<<<BATCH * (NTOK / TT), 256, 0, stream>>>(x, xn);
    attn_kernel<<<NTOK / BM * BATCH, 512, 0, stream>>>(xn, out);
}